// Round 4
// baseline (611.536 us; speedup 1.0000x reference)
//
#include <hip/hip_runtime.h>

#define HIDDEN 4096
#define NHEADS 32
#define NKV 8
#define HD 128
#define KVD 1024
#define QKVN 6144
#define SEQ 2048

typedef unsigned short u16;
typedef __bf16 bf16x8 __attribute__((ext_vector_type(8)));
typedef float f32x4 __attribute__((ext_vector_type(4)));
typedef unsigned short u16x4 __attribute__((ext_vector_type(4)));

__device__ __forceinline__ u16 f2b(float f) {
  union { float f; unsigned u; } v; v.f = f;
  unsigned r = (v.u + 0x7fffu + ((v.u >> 16) & 1u)) >> 16;
  return (u16)r;
}

__device__ __forceinline__ float b2f(u16 b) {
  union { unsigned u; float f; } v; v.u = ((unsigned)b) << 16;
  return v.f;
}

__device__ __forceinline__ void gl_lds16(const void* g, void* l) {
  __builtin_amdgcn_global_load_lds(
      (const __attribute__((address_space(1))) unsigned*)g,
      (__attribute__((address_space(3))) unsigned*)l, 16, 0, 0);
}

__device__ __forceinline__ f32x4 mfma16(bf16x8 a, bf16x8 b, f32x4 c) {
  return __builtin_amdgcn_mfma_f32_16x16x32_bf16(a, b, c, 0, 0, 0);
}

#define BARRIER() __builtin_amdgcn_s_barrier()
#define WAIT_VM6() asm volatile("s_waitcnt vmcnt(6)" ::: "memory")
#define WAIT_VM0() asm volatile("s_waitcnt vmcnt(0)" ::: "memory")

// ---------------- f32 -> bf16 convert ----------------
__global__ void cvt_bf16(const float* __restrict__ x, u16* __restrict__ y, int n) {
  int i = (blockIdx.x * 256 + threadIdx.x) * 4;
  if (i < n) {
    float4 v = *(const float4*)(x + i);
    u16x4 o = {f2b(v.x), f2b(v.y), f2b(v.z), f2b(v.w)};
    *(u16x4*)(y + i) = o;
  }
}

// ---------------- 64x64 tiled transpose + f32->bf16, vectorized ----------------
__global__ void transpose_cvt64(const float* __restrict__ W, long ldW,
                                u16* __restrict__ Wt, long ldT) {
  __shared__ float tile[64][65];
  long c0 = blockIdx.x * 64L, r0 = blockIdx.y * 64L;
  int tx = threadIdx.x, ty = threadIdx.y;
#pragma unroll
  for (int i = 0; i < 4; ++i) {
    float4 v = *(const float4*)(W + (r0 + ty + i * 16) * ldW + c0 + tx * 4);
    tile[ty + i * 16][tx * 4 + 0] = v.x;
    tile[ty + i * 16][tx * 4 + 1] = v.y;
    tile[ty + i * 16][tx * 4 + 2] = v.z;
    tile[ty + i * 16][tx * 4 + 3] = v.w;
  }
  __syncthreads();
#pragma unroll
  for (int i = 0; i < 4; ++i) {
    int c = ty + i * 16;
    u16x4 o = {f2b(tile[tx * 4 + 0][c]), f2b(tile[tx * 4 + 1][c]),
               f2b(tile[tx * 4 + 2][c]), f2b(tile[tx * 4 + 3][c])};
    *(u16x4*)(Wt + (c0 + c) * ldT + r0 + tx * 4) = o;
  }
}

// ---------------- 64x64 tiled transpose, bf16 -> bf16 (for V) ----------------
__global__ void transpose_b16(const u16* __restrict__ W, long ldW,
                              u16* __restrict__ Wt, long ldT) {
  __shared__ float tile[64][65];
  long c0 = blockIdx.x * 64L, r0 = blockIdx.y * 64L;
  int tx = threadIdx.x, ty = threadIdx.y;
#pragma unroll
  for (int i = 0; i < 4; ++i) {
    u16x4 v = *(const u16x4*)(W + (r0 + ty + i * 16) * ldW + c0 + tx * 4);
    tile[ty + i * 16][tx * 4 + 0] = b2f(v.x);
    tile[ty + i * 16][tx * 4 + 1] = b2f(v.y);
    tile[ty + i * 16][tx * 4 + 2] = b2f(v.z);
    tile[ty + i * 16][tx * 4 + 3] = b2f(v.w);
  }
  __syncthreads();
#pragma unroll
  for (int i = 0; i < 4; ++i) {
    int c = ty + i * 16;
    u16x4 o = {f2b(tile[tx * 4 + 0][c]), f2b(tile[tx * 4 + 1][c]),
               f2b(tile[tx * 4 + 2][c]), f2b(tile[tx * 4 + 3][c])};
    *(u16x4*)(Wt + (c0 + c) * ldT + r0 + tx * 4) = o;
  }
}

// ================= 256x256 8-phase bf16 GEMM, one-phase-ahead LDS prefetch =================
// C = A[M,K] * Bt[N,K]^T + bias.  512 thr = 8 waves (2M x 4N), per-wave 128x64 out.
// Each phase ISSUES the ds_reads for the NEXT phase's 16-MFMA block (software-pipelined
// LDS reads: the consuming MFMA's compiler dep-wait finds data returned; LDS drain of
// phase p+1 hides under MFMA of phase p). Quadrant order (0,0)(0,2)(4,0)(4,2) so each
// phase's prefetch writes a fragment set disjoint from the one its MFMA reads.
// Swizzle (T2): 16B-slot XOR (row&7); LDS written linearly by global_load_lds ->
// permutation applied to per-lane GLOBAL slot ((lane&7)^(lane>>3)); reads XOR with
// (l15&7). Stage stream (1 unit/phase): p1 A-R2(b1,T+1) | p2 A-R1(b0,T+2) |
// p3 B-H0(b0,T+2) | p4 B-H1(b0,T+2)+vmcnt6 | p5 A-R2(b0,T+2) | p6 A-R1(b1,T+3) |
// p7 B-H0(b1,T+3) | p8 B-H1(b1,T+3)+vmcnt6.  Hazard ledger (verified):
//  - p4 prefetch (b1 tile T+1): units staged prev-p6/p7/p8 + this-p1; p4 vmcnt6
//    retires through this-p1 -> landed. Reads issued AFTER the vmcnt.
//  - p8 prefetch (b0 tile T+2): units staged p2/p3/p4/p5; p8 vmcnt6 retires through
//    p5 -> landed (exactly tight).
//  - every stage's target region: last prefetch-read of it was dep-consumed >=1
//    barrier before the stage issues (checked per-phase).

#define LOAD_AF(lA, QM, DST)                                              \
  _Pragma("unroll") for (int mi_ = 0; mi_ < 4; ++mi_) {                   \
    const int ro_ = (wm * 128 + (QM) * 64 + mi_ * 16 + l15) * 64;         \
    DST[mi_][0] = *(const bf16x8*)&(lA)[ro_ + sq0];                       \
    DST[mi_][1] = *(const bf16x8*)&(lA)[ro_ + sq1];                       \
  }

#define LOAD_BF(lB, QN, DST)                                              \
  _Pragma("unroll") for (int nj_ = 0; nj_ < 2; ++nj_) {                   \
    const int ro_ = (wn * 64 + (QN) * 32 + nj_ * 16 + l15) * 64;          \
    DST[nj_][0] = *(const bf16x8*)&(lB)[ro_ + sq0];                       \
    DST[nj_][1] = *(const bf16x8*)&(lB)[ro_ + sq1];                       \
  }

#define MFMA_BLOCK(MI0, NJ0, AFARR, BFARR)                                \
  __builtin_amdgcn_s_setprio(1);                                          \
  _Pragma("unroll") for (int mi_ = 0; mi_ < 4; ++mi_)                     \
  _Pragma("unroll") for (int nj_ = 0; nj_ < 2; ++nj_)                     \
  _Pragma("unroll") for (int ks_ = 0; ks_ < 2; ++ks_)                     \
    acc[(MI0) + mi_][(NJ0) + nj_] =                                       \
        mfma16(AFARR[mi_][ks_], BFARR[nj_][ks_], acc[(MI0) + mi_][(NJ0) + nj_]); \
  __builtin_amdgcn_s_setprio(0);

#define STAGE_A(buf, u, kt)                                               \
  { char* d_ = dA[u] + (buf) * 32768;                                     \
    gl_lds16(aS[u][0] + (long)(kt) * 64, d_);                             \
    gl_lds16(aS[u][1] + (long)(kt) * 64, d_ + 1024); }

#define STAGE_B(buf, u, kt)                                               \
  { char* d_ = dB[u] + (buf) * 32768;                                     \
    gl_lds16(bS[u][0] + (long)(kt) * 64, d_);                             \
    gl_lds16(bS[u][1] + (long)(kt) * 64, d_ + 1024); }

template <bool OUT16>
__global__ __launch_bounds__(512) void gemm256_bt_bias(
    const u16* __restrict__ A, const u16* __restrict__ Bt,
    const float* __restrict__ bias, void* __restrict__ Cv,
    int M, int N, int K) {
  __shared__ u16 As[2][16384];
  __shared__ u16 Bs[2][16384];
  const int t = threadIdx.x;
  const int w = t >> 6, lane = t & 63;
  const int quad = lane >> 4, l15 = lane & 15;
  const int wm = w >> 2, wn = w & 3;
  const long m0 = blockIdx.y * 256L, n0 = blockIdx.x * 256L;
  const int NT = K >> 6;

  // swizzled 16B-slot byte offsets (u16 units) for fragment reads (ks=0 / ks=1)
  const int sq0 = ((quad ^ (l15 & 7)) << 3);
  const int sq1 = sq0 ^ 32;

  // staging: lane covers (row-in-8-block = lane>>3, slot = lane&7); global slot
  // pre-XORed with row&7 so the linear LDS write realizes the read-side swizzle.
  const int xs8 = ((lane & 7) ^ (lane >> 3)) * 8;
  const int sr = lane >> 3;
  const u16 *aS[2][2], *bS[2][2];
  char *dA[2], *dB[2];
  {
    const int ra = (w >> 2) * 128 + (w & 3) * 16;  // A unit base row (u adds 64)
    const int rb = w * 16;                         // B half base row (u adds 128)
#pragma unroll
    for (int u = 0; u < 2; ++u) {
#pragma unroll
      for (int j = 0; j < 2; ++j) {
        aS[u][j] = A + (m0 + ra + u * 64 + j * 8 + sr) * (long)K + xs8;
        bS[u][j] = Bt + (n0 + rb + u * 128 + j * 8 + sr) * (long)K + xs8;
      }
    }
    dA[0] = (char*)As + ra * 128;
    dA[1] = (char*)As + (ra + 64) * 128;
    dB[0] = (char*)Bs + rb * 128;
    dB[1] = (char*)Bs + (rb + 128) * 128;
  }

  f32x4 acc[8][4] = {};
  bf16x8 afL[4][2], afH[4][2], bfA[2][2], bfB[2][2];

  // ---- prologue: tile0 fully (8 loads) + tile1 {A-R1, B-H0, B-H1}; vmcnt(6)
  // retires tile0. Then prefetch p1's fragments (afL = A-QM0, bfA = B-QN0).
  STAGE_A(0, 0, 0); STAGE_A(0, 1, 0); STAGE_B(0, 0, 0); STAGE_B(0, 1, 0);
  STAGE_A(1, 0, 1); STAGE_B(1, 0, 1); STAGE_B(1, 1, 1);
  WAIT_VM6();
  BARRIER();
  LOAD_AF(As[0], 0, afL);
  LOAD_BF(Bs[0], 0, bfA);

  for (int T = 0; T < NT; T += 2) {
    const bool live = (T + 2 < NT);
    // ================= tile T (buf0) =================
    // p1: MFMA Q(0,0) on afL,bfA ; prefetch bfB (for p2)
    LOAD_BF(Bs[0], 1, bfB);
    STAGE_A(1, 1, T + 1);
    BARRIER();
    MFMA_BLOCK(0, 0, afL, bfA);
    BARRIER();
    // p2: MFMA Q(0,2) on afL,bfB ; prefetch afH (for p3)
    LOAD_AF(As[0], 1, afH);
    if (live) STAGE_A(0, 0, T + 2);
    BARRIER();
    MFMA_BLOCK(0, 2, afL, bfB);
    BARRIER();
    // p3: MFMA Q(4,0) on afH,bfA ; no prefetch
    if (live) STAGE_B(0, 0, T + 2);
    BARRIER();
    MFMA_BLOCK(4, 0, afH, bfA);
    BARRIER();
    // p4: MFMA Q(4,2) on afH,bfB ; vmcnt then prefetch afL,bfA for p5 (buf1)
    if (live) { STAGE_B(0, 1, T + 2); WAIT_VM6(); } else { WAIT_VM0(); }
    LOAD_AF(As[1], 0, afL);
    LOAD_BF(Bs[1], 0, bfA);
    BARRIER();
    MFMA_BLOCK(4, 2, afH, bfB);
    BARRIER();
    // ================= tile T+1 (buf1) =================
    // p5
    LOAD_BF(Bs[1], 1, bfB);
    if (live) STAGE_A(0, 1, T + 2);
    BARRIER();
    MFMA_BLOCK(0, 0, afL, bfA);
    BARRIER();
    // p6
    LOAD_AF(As[1], 1, afH);
    if (live) STAGE_A(1, 0, T + 3);
    BARRIER();
    MFMA_BLOCK(0, 2, afL, bfB);
    BARRIER();
    // p7
    if (live) STAGE_B(1, 0, T + 3);
    BARRIER();
    MFMA_BLOCK(4, 0, afH, bfA);
    BARRIER();
    // p8: vmcnt then prefetch afL,bfA for next p1 (buf0, tile T+2)
    if (live) { STAGE_B(1, 1, T + 3); WAIT_VM6(); } else { WAIT_VM0(); }
    LOAD_AF(As[0], 0, afL);
    LOAD_BF(Bs[0], 0, bfA);
    BARRIER();
    MFMA_BLOCK(4, 2, afH, bfB);
    BARRIER();
  }

  // ---- epilogue ----
#pragma unroll
  for (int mi = 0; mi < 8; ++mi) {
#pragma unroll
    for (int nj = 0; nj < 4; ++nj) {
      long n = n0 + wn * 64 + nj * 16 + l15;
      float bv = bias[n];
      long mr = m0 + wm * 128 + mi * 16 + quad * 4;
      if constexpr (OUT16) {
        u16* C = (u16*)Cv;
#pragma unroll
        for (int r = 0; r < 4; ++r)
          C[(mr + r) * (long)N + n] = f2b(acc[mi][nj][r] + bv);
      } else {
        float* C = (float*)Cv;
#pragma unroll
        for (int r = 0; r < 4; ++r)
          C[(mr + r) * (long)N + n] = acc[mi][nj][r] + bv;
      }
    }
  }
}

// ---------------- RoPE: QKVb bf16 -> Qr (h,s,d)*sc / Kr (kvh,s,d) bf16 ----------------
__global__ void rope_qk(const u16* __restrict__ qkv, const int* __restrict__ pos,
                        u16* __restrict__ Qr, u16* __restrict__ Kr) {
  int s = blockIdx.x;
  int hl = threadIdx.x >> 6;
  int d = threadIdx.x & 63;
  int h = blockIdx.y * 4 + hl;  // 0..39
  float p = (float)pos[s];
  float inv = __builtin_amdgcn_exp2f(-(float)d * (13.287712379549449f / 64.0f));
  float ang = p * inv;
  float cs, sn;
  __sincosf(ang, &sn, &cs);
  long base = (long)s * QKVN + (long)h * HD;
  float x1 = b2f(qkv[base + d]), x2 = b2f(qkv[base + d + 64]);
  float o1 = x1 * cs - x2 * sn, o2 = x2 * cs + x1 * sn;
  if (h < NHEADS) {
    const float sc = 0.12751744154f;  // log2(e)/sqrt(128)
    long ob = ((long)h * SEQ + s) * HD;
    Qr[ob + d] = f2b(o1 * sc);
    Qr[ob + d + 64] = f2b(o2 * sc);
  } else {
    long ob = ((long)(h - NHEADS) * SEQ + s) * HD;
    Kr[ob + d] = f2b(o1);
    Kr[ob + d + 64] = f2b(o2);
  }
}

// ---------------- flash-style causal GQA attention, paired q-tiles ----------------
__device__ __forceinline__ void attn_tile(
    const bf16x8 q[4], const u16* KsF, const u16* VsF, u16* Psw,
    bool diag, int wq, int quad, int l15, int sq, f32x4 Oa[8], f32x4& lacc,
    bf16x8 ones) {
  f32x4 s[4] = {};
#pragma unroll
  for (int ks = 0; ks < 4; ++ks) {
#pragma unroll
    for (int nj = 0; nj < 4; ++nj) {
      bf16x8 bk = *reinterpret_cast<const bf16x8*>(
          &KsF[ks * 2048 + (nj * 16 + l15) * 32 + sq * 8]);
      s[nj] = mfma16(q[ks], bk, s[nj]);
    }
  }
#pragma unroll
  for (int nj = 0; nj < 4; ++nj) {
    int key = nj * 16 + l15;
    int ksw = key >> 5, kc = key & 31;
    int khi = kc >> 3, klo = kc & 7;
#pragma unroll
    for (int r = 0; r < 4; ++r) {
      float x = s[nj][r];
      if (diag && key > wq + r) x = -3.0e30f;
      int row = quad * 4 + r;
      Psw[ksw * 512 + row * 32 + ((khi ^ ((row >> 1) & 3)) << 3) + klo] =
          f2b(__builtin_amdgcn_exp2f(x));
    }
  }
#pragma unroll
  for (int ks = 0; ks < 2; ++ks) {
    bf16x8 ap = *reinterpret_cast<const bf16x8*>(&Psw[ks * 512 + l15 * 32 + sq * 8]);
    lacc = mfma16(ap, ones, lacc);
#pragma unroll
    for (int dj = 0; dj < 8; ++dj) {
      bf16x8 bv = *reinterpret_cast<const bf16x8*>(
          &VsF[ks * 4096 + (dj * 16 + l15) * 32 + sq * 8]);
      Oa[dj] = mfma16(ap, bv, Oa[dj]);
    }
  }
}

__global__ __launch_bounds__(256) void attn_fused(
    const u16* __restrict__ Qr, const u16* __restrict__ Kr,
    const u16* __restrict__ Vt, u16* __restrict__ Ao) {
  __shared__ u16 Ks[4 * 64 * 32];
  __shared__ u16 Vs[2 * 128 * 32];
  __shared__ u16 Ps[4][2 * 16 * 32];
  const int px = blockIdx.x, h = blockIdx.y, kvh = h >> 2;
  const int qtA = px, qtB = (SEQ / 64 - 1) - px;
  const int t = threadIdx.x, w = t >> 6, lane = t & 63;
  const int quad = lane >> 4, l15 = lane & 15;
  const int sq = quad ^ ((l15 >> 1) & 3);
  const int wq = w * 16 + quad * 4;
  u16* Psw = &Ps[w][0];

  bf16x8 ones;
  {
    union { u16 u[8]; bf16x8 v; } ou;
#pragma unroll
    for (int i = 0; i < 8; ++i) ou.u[i] = 0x3F80;
    ones = ou.v;
  }

  const long go = (long)(w * 16 + (lane >> 2)) * HD +
                  (long)(((lane & 3) ^ ((lane >> 3) & 3)) * 8);

  bf16x8 qA[4], qB[4];
  {
    const u16* QgA = Qr + ((long)h * SEQ + qtA * 64) * HD;
    const u16* QgB = Qr + ((long)h * SEQ + qtB * 64) * HD;
#pragma unroll
    for (int j = 0; j < 4; ++j) {
      gl_lds16(QgA + go + j * 32, (char*)Ks + j * 4096 + w * 1024);
      gl_lds16(QgB + go + j * 32, (char*)Vs + j * 4096 + w * 1024);
    }
    __syncthreads();
#pragma unroll
    for (int j = 0; j < 4; ++j) {
      qA[j] = *reinterpret_cast<const bf16x8*>(&Ks[j * 2048 + (w * 16 + l15) * 32 + sq * 8]);
      qB[j] = *reinterpret_cast<const bf16x8*>(&Vs[j * 2048 + (w * 16 + l15) * 32 + sq * 8]);
    }
    __syncthreads();
  }

  f32x4 OaA[8] = {}, OaB[8] = {};
  f32x4 lA = {}, lB = {};
  const u16* Kg0 = Kr + (long)kvh * SEQ * HD;
  const u16* Vg0 = Vt + (long)kvh * HD * SEQ;

  for (int kt = 0; kt <= qtB; ++kt) {
    const int k0 = kt * 64;
    {
      const u16* Kg = Kg0 + (long)k0 * HD;
#pragma unroll
      for (int j = 0; j < 4; ++j)
        gl_lds16(Kg + go + j * 32, (char*)Ks + j * 4096 + w * 1024);
      const u16* Vg = Vg0 + k0;
      const int vc = ((lane & 3) ^ ((lane >> 3) & 3)) * 8;
#pragma unroll
      for (int j = 0; j < 4; ++j) {
        int dd = (j & 1) * 64 + w * 16 + (lane >> 2);
        int ks = j >> 1;
        gl_lds16(Vg + (long)dd * SEQ + ks * 32 + vc, (char*)Vs + j * 4096 + w * 1024);
      }
    }
    __syncthreads();

    attn_tile(qB, Ks, Vs, Psw, kt == qtB, wq, quad, l15, sq, OaB, lB, ones);
    if (kt <= qtA)
      attn_tile(qA, Ks, Vs, Psw, kt == qtA, wq, quad, l15, sq, OaA, lA, ones);

    __syncthreads();
  }

#pragma unroll
  for (int r = 0; r < 4; ++r) {
    float invA = 1.0f / lA[r];
    float invB = 1.0f / lB[r];
    long rowA = (long)(qtA * 64 + w * 16 + quad * 4 + r) * HIDDEN + (long)h * HD;
    long rowB = (long)(qtB * 64 + w * 16 + quad * 4 + r) * HIDDEN + (long)h * HD;
#pragma unroll
    for (int dj = 0; dj < 8; ++dj) {
      Ao[rowA + dj * 16 + l15] = f2b(OaA[dj][r] * invA);
      Ao[rowB + dj * 16 + l15] = f2b(OaB[dj][r] * invB);
    }
  }
}

extern "C" void kernel_launch(void* const* d_in, const int* in_sizes, int n_in,
                              void* d_out, int out_size, void* d_ws, size_t ws_size,
                              hipStream_t stream) {
  const int* positions = (const int*)d_in[0];
  const float* hidden = (const float*)d_in[1];
  const float* Wqkv = (const float*)d_in[2];
  const float* bqkv = (const float*)d_in[3];
  const float* Wproj = (const float*)d_in[4];
  const float* bproj = (const float*)d_in[5];
  float* out = (float*)d_out;
  char* ws = (char*)d_ws;

  u16* Wqt = (u16*)(ws);                  // 6144x4096 bf16   (50331648 B)
  u16* Wpt = (u16*)(ws + 50331648L);      // 4096x4096 bf16   (33554432 B)
  u16* Xb = (u16*)(ws + 83886080L);       // 2048x4096 bf16   (16777216 B)
  u16* QKVb = (u16*)(ws + 100663296L);    // 2048x6144 bf16   (25165824 B)
  u16* Qr = (u16*)(ws + 125829120L);      // 32x2048x128 bf16 (16777216 B)
  u16* Kr = (u16*)(ws + 142606336L);      // 8x2048x128 bf16  (4194304 B)
  u16* Vt = (u16*)(ws + 146800640L);      // 8x128x2048 bf16  (4194304 B)
  u16* Ao = (u16*)(ws + 150994944L);      // 2048x4096 bf16   (16777216 B)

  cvt_bf16<<<8192, 256, 0, stream>>>(hidden, Xb, SEQ * HIDDEN);
  transpose_cvt64<<<dim3(QKVN / 64, HIDDEN / 64), dim3(16, 16), 0, stream>>>(Wqkv, QKVN, Wqt, HIDDEN);
  transpose_cvt64<<<dim3(HIDDEN / 64, HIDDEN / 64), dim3(16, 16), 0, stream>>>(Wproj, HIDDEN, Wpt, HIDDEN);
  gemm256_bt_bias<true><<<dim3(QKVN / 256, SEQ / 256), 512, 0, stream>>>(Xb, Wqt, bqkv, QKVb, SEQ, QKVN, HIDDEN);
  rope_qk<<<dim3(SEQ, 10), 256, 0, stream>>>(QKVb, positions, Qr, Kr);
  transpose_b16<<<dim3(KVD / 64, SEQ / 64), dim3(16, 16), 0, stream>>>(QKVb + 5120, QKVN, Vt, SEQ);
  attn_fused<<<dim3(SEQ / 128, NHEADS), 256, 0, stream>>>(Qr, Kr, Vt, Ao);
  gemm256_bt_bias<false><<<dim3(HIDDEN / 256, SEQ / 256), 512, 0, stream>>>(Ao, Wpt, bproj, out, SEQ, HIDDEN, HIDDEN);
}

// Round 5
// 555.763 us; speedup vs baseline: 1.1004x; 1.1004x over previous
//
#include <hip/hip_runtime.h>

#define HIDDEN 4096
#define NHEADS 32
#define NKV 8
#define HD 128
#define KVD 1024
#define QKVN 6144
#define SEQ 2048

typedef unsigned short u16;
typedef __bf16 bf16x8 __attribute__((ext_vector_type(8)));
typedef float f32x4 __attribute__((ext_vector_type(4)));
typedef unsigned short u16x4 __attribute__((ext_vector_type(4)));

__device__ __forceinline__ u16 f2b(float f) {
  union { float f; unsigned u; } v; v.f = f;
  unsigned r = (v.u + 0x7fffu + ((v.u >> 16) & 1u)) >> 16;
  return (u16)r;
}

__device__ __forceinline__ float b2f(u16 b) {
  union { unsigned u; float f; } v; v.u = ((unsigned)b) << 16;
  return v.f;
}

__device__ __forceinline__ void gl_lds16(const void* g, void* l) {
  __builtin_amdgcn_global_load_lds(
      (const __attribute__((address_space(1))) unsigned*)g,
      (__attribute__((address_space(3))) unsigned*)l, 16, 0, 0);
}

__device__ __forceinline__ f32x4 mfma16(bf16x8 a, bf16x8 b, f32x4 c) {
  return __builtin_amdgcn_mfma_f32_16x16x32_bf16(a, b, c, 0, 0, 0);
}

#define BARRIER() __builtin_amdgcn_s_barrier()
#define WAIT_LGKM0() asm volatile("s_waitcnt lgkmcnt(0)" ::: "memory")
#define WAIT_VM6() asm volatile("s_waitcnt vmcnt(6)" ::: "memory")
#define WAIT_VM0() asm volatile("s_waitcnt vmcnt(0)" ::: "memory")

// ---------------- f32 -> bf16 convert ----------------
__global__ void cvt_bf16(const float* __restrict__ x, u16* __restrict__ y, int n) {
  int i = (blockIdx.x * 256 + threadIdx.x) * 4;
  if (i < n) {
    float4 v = *(const float4*)(x + i);
    u16x4 o = {f2b(v.x), f2b(v.y), f2b(v.z), f2b(v.w)};
    *(u16x4*)(y + i) = o;
  }
}

// ---------------- 64x64 tiled transpose + f32->bf16, vectorized ----------------
__global__ void transpose_cvt64(const float* __restrict__ W, long ldW,
                                u16* __restrict__ Wt, long ldT) {
  __shared__ float tile[64][65];
  long c0 = blockIdx.x * 64L, r0 = blockIdx.y * 64L;
  int tx = threadIdx.x, ty = threadIdx.y;
#pragma unroll
  for (int i = 0; i < 4; ++i) {
    float4 v = *(const float4*)(W + (r0 + ty + i * 16) * ldW + c0 + tx * 4);
    tile[ty + i * 16][tx * 4 + 0] = v.x;
    tile[ty + i * 16][tx * 4 + 1] = v.y;
    tile[ty + i * 16][tx * 4 + 2] = v.z;
    tile[ty + i * 16][tx * 4 + 3] = v.w;
  }
  __syncthreads();
#pragma unroll
  for (int i = 0; i < 4; ++i) {
    int c = ty + i * 16;
    u16x4 o = {f2b(tile[tx * 4 + 0][c]), f2b(tile[tx * 4 + 1][c]),
               f2b(tile[tx * 4 + 2][c]), f2b(tile[tx * 4 + 3][c])};
    *(u16x4*)(Wt + (c0 + c) * ldT + r0 + tx * 4) = o;
  }
}

// ---------------- 64x64 tiled transpose, bf16 -> bf16 (for V) ----------------
__global__ void transpose_b16(const u16* __restrict__ W, long ldW,
                              u16* __restrict__ Wt, long ldT) {
  __shared__ float tile[64][65];
  long c0 = blockIdx.x * 64L, r0 = blockIdx.y * 64L;
  int tx = threadIdx.x, ty = threadIdx.y;
#pragma unroll
  for (int i = 0; i < 4; ++i) {
    u16x4 v = *(const u16x4*)(W + (r0 + ty + i * 16) * ldW + c0 + tx * 4);
    tile[ty + i * 16][tx * 4 + 0] = b2f(v.x);
    tile[ty + i * 16][tx * 4 + 1] = b2f(v.y);
    tile[ty + i * 16][tx * 4 + 2] = b2f(v.z);
    tile[ty + i * 16][tx * 4 + 3] = b2f(v.w);
  }
  __syncthreads();
#pragma unroll
  for (int i = 0; i < 4; ++i) {
    int c = ty + i * 16;
    u16x4 o = {f2b(tile[tx * 4 + 0][c]), f2b(tile[tx * 4 + 1][c]),
               f2b(tile[tx * 4 + 2][c]), f2b(tile[tx * 4 + 3][c])};
    *(u16x4*)(Wt + (c0 + c) * ldT + r0 + tx * 4) = o;
  }
}

// ================= 256x256 8-phase bf16 GEMM (round-3 schedule + ks-outer MFMA) ========
// C = A[M,K]*Bt[N,K]^T (+bias). 512 thr = 8 waves (2M x 4N), per-wave 128x64 out.
// In-phase ds_reads (round-3 measured best). MFMA order ks->mi->nj: consecutive
// MFMAs hit distinct acc (dep distance 8, covered by pipe occupancy) instead of
// dependent ks-pairs at distance 1.
// Split-K support: blockIdx.z selects K-half (kOff = z*K); LDK is the full row
// stride; MODE 2 writes raw f32 partial (z=0 -> Cv, z=1 -> Cv2), summed by add2_bias.
// Swizzle (T2): 16B-slot XOR (row&7); LDS written linearly by global_load_lds ->
// permutation applied to per-lane GLOBAL slot ((lane&7)^(lane>>3)); reads XOR (l15&7).
// Stage stream (1 unit/phase): p1 A-R2(b1,T+1) | p2 A-R1(b0,T+2) | p3 B-H0(b0,T+2)
// | p4 B-H1(b0,T+2)+vmcnt6 | p5 A-R2(b0,T+2) | p6 A-R1(b1,T+3) | p7 B-H0(b1,T+3) |
// p8 B-H1(b1,T+3)+vmcnt6.  (Hazard ledger verified in round 3; passed harness.)

#define LOAD_AF(lA, QM)                                                   \
  _Pragma("unroll") for (int mi_ = 0; mi_ < 4; ++mi_) {                   \
    const int ro_ = (wm * 128 + (QM) * 64 + mi_ * 16 + l15) * 64;         \
    af[mi_][0] = *(const bf16x8*)&(lA)[ro_ + sq0];                        \
    af[mi_][1] = *(const bf16x8*)&(lA)[ro_ + sq1];                        \
  }

#define LOAD_BF(lB, QN, DST)                                              \
  _Pragma("unroll") for (int nj_ = 0; nj_ < 2; ++nj_) {                   \
    const int ro_ = (wn * 64 + (QN) * 32 + nj_ * 16 + l15) * 64;          \
    DST[nj_][0] = *(const bf16x8*)&(lB)[ro_ + sq0];                       \
    DST[nj_][1] = *(const bf16x8*)&(lB)[ro_ + sq1];                       \
  }

#define MFMA_BLOCK(MI0, NJ0, BFARR)                                       \
  __builtin_amdgcn_s_setprio(1);                                          \
  _Pragma("unroll") for (int ks_ = 0; ks_ < 2; ++ks_)                     \
  _Pragma("unroll") for (int mi_ = 0; mi_ < 4; ++mi_)                     \
  _Pragma("unroll") for (int nj_ = 0; nj_ < 2; ++nj_)                     \
    acc[(MI0) + mi_][(NJ0) + nj_] =                                       \
        mfma16(af[mi_][ks_], BFARR[nj_][ks_], acc[(MI0) + mi_][(NJ0) + nj_]); \
  __builtin_amdgcn_s_setprio(0);

#define STAGE_A(buf, u, kt)                                               \
  { char* d_ = dA[u] + (buf) * 32768;                                     \
    gl_lds16(aS[u][0] + (long)(kt) * 64, d_);                             \
    gl_lds16(aS[u][1] + (long)(kt) * 64, d_ + 1024); }

#define STAGE_B(buf, u, kt)                                               \
  { char* d_ = dB[u] + (buf) * 32768;                                     \
    gl_lds16(bS[u][0] + (long)(kt) * 64, d_);                             \
    gl_lds16(bS[u][1] + (long)(kt) * 64, d_ + 1024); }

// MODE 1: bf16 out, +bias.  MODE 2: f32 raw partial (split-K), z picks Cv/Cv2.
template <int MODE>
__global__ __launch_bounds__(512) void gemm256_bt_bias(
    const u16* __restrict__ A, const u16* __restrict__ Bt,
    const float* __restrict__ bias, void* __restrict__ Cv, void* __restrict__ Cv2,
    int M, int N, int K, long LDK) {
  __shared__ u16 As[2][16384];
  __shared__ u16 Bs[2][16384];
  const int t = threadIdx.x;
  const int w = t >> 6, lane = t & 63;
  const int quad = lane >> 4, l15 = lane & 15;
  const int wm = w >> 2, wn = w & 3;
  const long m0 = blockIdx.y * 256L, n0 = blockIdx.x * 256L;
  const long kOff = (long)blockIdx.z * K;
  const int NT = K >> 6;

  const int sq0 = ((quad ^ (l15 & 7)) << 3);
  const int sq1 = sq0 ^ 32;

  const int xs8 = ((lane & 7) ^ (lane >> 3)) * 8;
  const int sr = lane >> 3;
  const u16 *aS[2][2], *bS[2][2];
  char *dA[2], *dB[2];
  {
    const int ra = (w >> 2) * 128 + (w & 3) * 16;  // A unit base row (u adds 64)
    const int rb = w * 16;                         // B half base row (u adds 128)
#pragma unroll
    for (int u = 0; u < 2; ++u) {
#pragma unroll
      for (int j = 0; j < 2; ++j) {
        aS[u][j] = A + (m0 + ra + u * 64 + j * 8 + sr) * LDK + kOff + xs8;
        bS[u][j] = Bt + (n0 + rb + u * 128 + j * 8 + sr) * LDK + kOff + xs8;
      }
    }
    dA[0] = (char*)As + ra * 128;
    dA[1] = (char*)As + (ra + 64) * 128;
    dB[0] = (char*)Bs + rb * 128;
    dB[1] = (char*)Bs + (rb + 128) * 128;
  }

  f32x4 acc[8][4] = {};
  bf16x8 af[4][2], bfA[2][2], bfB[2][2];

  // ---- prologue: tile0 fully (8 loads) + tile1 {A-R1, B-H0, B-H1}; vmcnt(6)
  // retires exactly tile0's 8 loads. Loop p1 supplies tile1's A-R2.
  STAGE_A(0, 0, 0); STAGE_A(0, 1, 0); STAGE_B(0, 0, 0); STAGE_B(0, 1, 0);
  STAGE_A(1, 0, 1); STAGE_B(1, 0, 1); STAGE_B(1, 1, 1);
  WAIT_VM6();
  BARRIER();

  for (int T = 0; T < NT; T += 2) {
    const bool live = (T + 2 < NT);
    // ================= tile T (buf0) =================
    // p1
    LOAD_AF(As[0], 0);
    LOAD_BF(Bs[0], 0, bfA);
    STAGE_A(1, 1, T + 1);
    BARRIER(); WAIT_LGKM0();
    MFMA_BLOCK(0, 0, bfA);
    BARRIER();
    // p2
    LOAD_BF(Bs[0], 1, bfB);
    if (live) STAGE_A(0, 0, T + 2);
    BARRIER(); WAIT_LGKM0();
    MFMA_BLOCK(0, 2, bfB);
    BARRIER();
    // p3
    LOAD_AF(As[0], 1);
    if (live) STAGE_B(0, 0, T + 2);
    BARRIER(); WAIT_LGKM0();
    MFMA_BLOCK(4, 2, bfB);
    BARRIER();
    // p4
    if (live) { STAGE_B(0, 1, T + 2); WAIT_VM6(); } else { WAIT_VM0(); }
    BARRIER();
    MFMA_BLOCK(4, 0, bfA);
    BARRIER();
    // ================= tile T+1 (buf1) =================
    // p5
    LOAD_AF(As[1], 0);
    LOAD_BF(Bs[1], 0, bfA);
    if (live) STAGE_A(0, 1, T + 2);
    BARRIER(); WAIT_LGKM0();
    MFMA_BLOCK(0, 0, bfA);
    BARRIER();
    // p6
    LOAD_BF(Bs[1], 1, bfB);
    if (live) STAGE_A(1, 0, T + 3);
    BARRIER(); WAIT_LGKM0();
    MFMA_BLOCK(0, 2, bfB);
    BARRIER();
    // p7
    LOAD_AF(As[1], 1);
    if (live) STAGE_B(1, 0, T + 3);
    BARRIER(); WAIT_LGKM0();
    MFMA_BLOCK(4, 2, bfB);
    BARRIER();
    // p8
    if (live) { STAGE_B(1, 1, T + 3); WAIT_VM6(); } else { WAIT_VM0(); }
    BARRIER();
    MFMA_BLOCK(4, 0, bfA);
    BARRIER();
  }

  // ---- epilogue ----
#pragma unroll
  for (int mi = 0; mi < 8; ++mi) {
#pragma unroll
    for (int nj = 0; nj < 4; ++nj) {
      long n = n0 + wn * 64 + nj * 16 + l15;
      long mr = m0 + wm * 128 + mi * 16 + quad * 4;
      if constexpr (MODE == 1) {
        float bv = bias[n];
        u16* C = (u16*)Cv;
#pragma unroll
        for (int r = 0; r < 4; ++r)
          C[(mr + r) * (long)N + n] = f2b(acc[mi][nj][r] + bv);
      } else {
        float* C = blockIdx.z ? (float*)Cv2 : (float*)Cv;
#pragma unroll
        for (int r = 0; r < 4; ++r)
          C[(mr + r) * (long)N + n] = acc[mi][nj][r];
      }
    }
  }
}

// ---------------- split-K reduce: out = out + P1 + bias ----------------
__global__ void add2_bias(float* __restrict__ o, const float* __restrict__ p1,
                          const float* __restrict__ bias) {
  int i = (blockIdx.x * 256 + threadIdx.x) * 4;
  float4 a = *(float4*)(o + i);
  float4 b = *(const float4*)(p1 + i);
  float4 c = *(const float4*)(bias + (i & (HIDDEN - 1)));
  a.x += b.x + c.x; a.y += b.y + c.y; a.z += b.z + c.z; a.w += b.w + c.w;
  *(float4*)(o + i) = a;
}

// ---------------- RoPE: QKVb bf16 -> Qr (h,s,d)*sc / Kr (kvh,s,d) bf16 ----------------
__global__ void rope_qk(const u16* __restrict__ qkv, const int* __restrict__ pos,
                        u16* __restrict__ Qr, u16* __restrict__ Kr) {
  int s = blockIdx.x;
  int hl = threadIdx.x >> 6;
  int d = threadIdx.x & 63;
  int h = blockIdx.y * 4 + hl;  // 0..39
  float p = (float)pos[s];
  float inv = __builtin_amdgcn_exp2f(-(float)d * (13.287712379549449f / 64.0f));
  float ang = p * inv;
  float cs, sn;
  __sincosf(ang, &sn, &cs);
  long base = (long)s * QKVN + (long)h * HD;
  float x1 = b2f(qkv[base + d]), x2 = b2f(qkv[base + d + 64]);
  float o1 = x1 * cs - x2 * sn, o2 = x2 * cs + x1 * sn;
  if (h < NHEADS) {
    const float sc = 0.12751744154f;  // log2(e)/sqrt(128)
    long ob = ((long)h * SEQ + s) * HD;
    Qr[ob + d] = f2b(o1 * sc);
    Qr[ob + d + 64] = f2b(o2 * sc);
  } else {
    long ob = ((long)(h - NHEADS) * SEQ + s) * HD;
    Kr[ob + d] = f2b(o1);
    Kr[ob + d + 64] = f2b(o2);
  }
}

// ---------------- flash-style causal GQA attention, paired q-tiles ----------------
__device__ __forceinline__ void attn_tile(
    const bf16x8 q[4], const u16* KsF, const u16* VsF, u16* Psw,
    bool diag, int wq, int quad, int l15, int sq, f32x4 Oa[8], f32x4& lacc,
    bf16x8 ones) {
  f32x4 s[4] = {};
#pragma unroll
  for (int ks = 0; ks < 4; ++ks) {
#pragma unroll
    for (int nj = 0; nj < 4; ++nj) {
      bf16x8 bk = *reinterpret_cast<const bf16x8*>(
          &KsF[ks * 2048 + (nj * 16 + l15) * 32 + sq * 8]);
      s[nj] = mfma16(q[ks], bk, s[nj]);
    }
  }
#pragma unroll
  for (int nj = 0; nj < 4; ++nj) {
    int key = nj * 16 + l15;
    int ksw = key >> 5, kc = key & 31;
    int khi = kc >> 3, klo = kc & 7;
#pragma unroll
    for (int r = 0; r < 4; ++r) {
      float x = s[nj][r];
      if (diag && key > wq + r) x = -3.0e30f;
      int row = quad * 4 + r;
      Psw[ksw * 512 + row * 32 + ((khi ^ ((row >> 1) & 3)) << 3) + klo] =
          f2b(__builtin_amdgcn_exp2f(x));
    }
  }
#pragma unroll
  for (int ks = 0; ks < 2; ++ks) {
    bf16x8 ap = *reinterpret_cast<const bf16x8*>(&Psw[ks * 512 + l15 * 32 + sq * 8]);
    lacc = mfma16(ap, ones, lacc);
#pragma unroll
    for (int dj = 0; dj < 8; ++dj) {
      bf16x8 bv = *reinterpret_cast<const bf16x8*>(
          &VsF[ks * 4096 + (dj * 16 + l15) * 32 + sq * 8]);
      Oa[dj] = mfma16(ap, bv, Oa[dj]);
    }
  }
}

__global__ __launch_bounds__(256) void attn_fused(
    const u16* __restrict__ Qr, const u16* __restrict__ Kr,
    const u16* __restrict__ Vt, u16* __restrict__ Ao) {
  __shared__ u16 Ks[4 * 64 * 32];
  __shared__ u16 Vs[2 * 128 * 32];
  __shared__ u16 Ps[4][2 * 16 * 32];
  const int px = blockIdx.x, h = blockIdx.y, kvh = h >> 2;
  const int qtA = px, qtB = (SEQ / 64 - 1) - px;
  const int t = threadIdx.x, w = t >> 6, lane = t & 63;
  const int quad = lane >> 4, l15 = lane & 15;
  const int sq = quad ^ ((l15 >> 1) & 3);
  const int wq = w * 16 + quad * 4;
  u16* Psw = &Ps[w][0];

  bf16x8 ones;
  {
    union { u16 u[8]; bf16x8 v; } ou;
#pragma unroll
    for (int i = 0; i < 8; ++i) ou.u[i] = 0x3F80;
    ones = ou.v;
  }

  const long go = (long)(w * 16 + (lane >> 2)) * HD +
                  (long)(((lane & 3) ^ ((lane >> 3) & 3)) * 8);

  bf16x8 qA[4], qB[4];
  {
    const u16* QgA = Qr + ((long)h * SEQ + qtA * 64) * HD;
    const u16* QgB = Qr + ((long)h * SEQ + qtB * 64) * HD;
#pragma unroll
    for (int j = 0; j < 4; ++j) {
      gl_lds16(QgA + go + j * 32, (char*)Ks + j * 4096 + w * 1024);
      gl_lds16(QgB + go + j * 32, (char*)Vs + j * 4096 + w * 1024);
    }
    __syncthreads();
#pragma unroll
    for (int j = 0; j < 4; ++j) {
      qA[j] = *reinterpret_cast<const bf16x8*>(&Ks[j * 2048 + (w * 16 + l15) * 32 + sq * 8]);
      qB[j] = *reinterpret_cast<const bf16x8*>(&Vs[j * 2048 + (w * 16 + l15) * 32 + sq * 8]);
    }
    __syncthreads();
  }

  f32x4 OaA[8] = {}, OaB[8] = {};
  f32x4 lA = {}, lB = {};
  const u16* Kg0 = Kr + (long)kvh * SEQ * HD;
  const u16* Vg0 = Vt + (long)kvh * HD * SEQ;

  for (int kt = 0; kt <= qtB; ++kt) {
    const int k0 = kt * 64;
    {
      const u16* Kg = Kg0 + (long)k0 * HD;
#pragma unroll
      for (int j = 0; j < 4; ++j)
        gl_lds16(Kg + go + j * 32, (char*)Ks + j * 4096 + w * 1024);
      const u16* Vg = Vg0 + k0;
      const int vc = ((lane & 3) ^ ((lane >> 3) & 3)) * 8;
#pragma unroll
      for (int j = 0; j < 4; ++j) {
        int dd = (j & 1) * 64 + w * 16 + (lane >> 2);
        int ks = j >> 1;
        gl_lds16(Vg + (long)dd * SEQ + ks * 32 + vc, (char*)Vs + j * 4096 + w * 1024);
      }
    }
    __syncthreads();

    attn_tile(qB, Ks, Vs, Psw, kt == qtB, wq, quad, l15, sq, OaB, lB, ones);
    if (kt <= qtA)
      attn_tile(qA, Ks, Vs, Psw, kt == qtA, wq, quad, l15, sq, OaA, lA, ones);

    __syncthreads();
  }

#pragma unroll
  for (int r = 0; r < 4; ++r) {
    float invA = 1.0f / lA[r];
    float invB = 1.0f / lB[r];
    long rowA = (long)(qtA * 64 + w * 16 + quad * 4 + r) * HIDDEN + (long)h * HD;
    long rowB = (long)(qtB * 64 + w * 16 + quad * 4 + r) * HIDDEN + (long)h * HD;
#pragma unroll
    for (int dj = 0; dj < 8; ++dj) {
      Ao[rowA + dj * 16 + l15] = f2b(OaA[dj][r] * invA);
      Ao[rowB + dj * 16 + l15] = f2b(OaB[dj][r] * invB);
    }
  }
}

extern "C" void kernel_launch(void* const* d_in, const int* in_sizes, int n_in,
                              void* d_out, int out_size, void* d_ws, size_t ws_size,
                              hipStream_t stream) {
  const int* positions = (const int*)d_in[0];
  const float* hidden = (const float*)d_in[1];
  const float* Wqkv = (const float*)d_in[2];
  const float* bqkv = (const float*)d_in[3];
  const float* Wproj = (const float*)d_in[4];
  const float* bproj = (const float*)d_in[5];
  float* out = (float*)d_out;
  char* ws = (char*)d_ws;

  u16* Wqt = (u16*)(ws);                  // 6144x4096 bf16   (50331648 B)
  u16* Wpt = (u16*)(ws + 50331648L);      // 4096x4096 bf16   (33554432 B)
  u16* Xb = (u16*)(ws + 83886080L);       // 2048x4096 bf16   (16777216 B)
  u16* QKVb = (u16*)(ws + 100663296L);    // 2048x6144 bf16   (25165824 B)
  u16* Qr = (u16*)(ws + 125829120L);      // 32x2048x128 bf16 (16777216 B)
  u16* Kr = (u16*)(ws + 142606336L);      // 8x2048x128 bf16  (4194304 B)
  u16* Vt = (u16*)(ws + 146800640L);      // 8x128x2048 bf16  (4194304 B)
  u16* Ao = (u16*)(ws + 150994944L);      // 2048x4096 bf16   (16777216 B)
  // P1 partial (proj split-K, z=1): reuses QKVb+Qr (dead after attn inputs built)
  float* P1 = (float*)(ws + 100663296L);  // 2048x4096 f32    (33554432 B)

  cvt_bf16<<<8192, 256, 0, stream>>>(hidden, Xb, SEQ * HIDDEN);
  transpose_cvt64<<<dim3(QKVN / 64, HIDDEN / 64), dim3(16, 16), 0, stream>>>(Wqkv, QKVN, Wqt, HIDDEN);
  transpose_cvt64<<<dim3(HIDDEN / 64, HIDDEN / 64), dim3(16, 16), 0, stream>>>(Wproj, HIDDEN, Wpt, HIDDEN);
  gemm256_bt_bias<1><<<dim3(QKVN / 256, SEQ / 256), 512, 0, stream>>>(
      Xb, Wqt, bqkv, QKVb, nullptr, SEQ, QKVN, HIDDEN, HIDDEN);
  rope_qk<<<dim3(SEQ, 10), 256, 0, stream>>>(QKVb, positions, Qr, Kr);
  transpose_b16<<<dim3(KVD / 64, SEQ / 64), dim3(16, 16), 0, stream>>>(QKVb + 5120, QKVN, Vt, SEQ);
  attn_fused<<<dim3(SEQ / 128, NHEADS), 256, 0, stream>>>(Qr, Kr, Vt, Ao);
  gemm256_bt_bias<2><<<dim3(HIDDEN / 256, SEQ / 256, 2), 512, 0, stream>>>(
      Ao, Wpt, bproj, out, P1, SEQ, HIDDEN, HIDDEN / 2, HIDDEN);
  add2_bias<<<SEQ * HIDDEN / 1024, 256, 0, stream>>>(out, P1, bproj);
}